// Round 16
// baseline (80.027 us; speedup 1.0000x reference)
//
#include <hip/hip_runtime.h>
#include <hip/hip_bf16.h>

#define B_  4
#define N_  512
#define D_  128
#define H_  8
#define DK  16
#define DFF 512
#define NB  32
#define KS  8            // attention key-split

// ---------------- QKV projections + fused QE table (384 blocks, ROWS=4) --------------
__global__ __launch_bounds__(256) void qkv_qe_kernel(
    const float* __restrict__ A,
    const float* __restrict__ WQ, const float* __restrict__ WK, const float* __restrict__ WV,
    const float* __restrict__ emb,
    float* __restrict__ Qo, float* __restrict__ Ko, float* __restrict__ Vo,
    float* __restrict__ QE)
{
    const float* Bw = blockIdx.z == 0 ? WQ : (blockIdx.z == 1 ? WK : WV);
    float*       C  = blockIdx.z == 0 ? Qo : (blockIdx.z == 1 ? Ko : Vo);
    const int wave = threadIdx.x >> 6;
    const int lane = threadIdx.x & 63;
    const int rbase = __builtin_amdgcn_readfirstlane((blockIdx.x * 4 + wave) * 4);
    const int col = lane * 2;

    float acc[4][2] = {};
#pragma unroll 2
    for (int k0 = 0; k0 < D_; k0 += 4) {
        float4 a4[4];
#pragma unroll
        for (int j = 0; j < 4; ++j)
            a4[j] = *(const float4*)&A[(size_t)(rbase + j) * D_ + k0];
#pragma unroll
        for (int kk = 0; kk < 4; ++kk) {
            float2 bv = *(const float2*)&Bw[(size_t)(k0 + kk) * D_ + col];
#pragma unroll
            for (int j = 0; j < 4; ++j) {
                float x = (&a4[j].x)[kk];
                acc[j][0] += x * bv.x; acc[j][1] += x * bv.y;
            }
        }
    }
#pragma unroll
    for (int j = 0; j < 4; ++j)
        *(float2*)&C[(size_t)(rbase + j) * D_ + col] = make_float2(acc[j][0], acc[j][1]);

    if (blockIdx.z == 0) {
        __shared__ float Qls[16][132];
#pragma unroll
        for (int j = 0; j < 4; ++j)
            *(float2*)&Qls[wave * 4 + j][col] = make_float2(acc[j][0], acc[j][1]);
        __syncthreads();
        const int r  = threadIdx.x >> 4;
        const int hh = (threadIdx.x & 15) >> 1;
        const int k0 = (threadIdx.x & 1) * 16;
        const int grow = blockIdx.x * 16 + r;
        const float4* qv = (const float4*)&Qls[r][hh * DK];
        const float4 qa = qv[0], qb = qv[1], qc = qv[2], qd = qv[3];
        float* qe_out = QE + ((size_t)grow * H_ + hh) * NB + k0;
#pragma unroll 4
        for (int k = 0; k < 16; ++k) {
            const float4* ep = (const float4*)(emb + (size_t)(k0 + k) * D_ + hh * DK);
            float4 e0 = ep[0], e1 = ep[1], e2 = ep[2], e3 = ep[3];
            float d0 = fmaf(qa.x,e0.x, fmaf(qa.y,e0.y, fmaf(qa.z,e0.z, qa.w*e0.w)));
            float d1 = fmaf(qb.x,e1.x, fmaf(qb.y,e1.y, fmaf(qb.z,e1.z, qb.w*e1.w)));
            float d2 = fmaf(qc.x,e2.x, fmaf(qc.y,e2.y, fmaf(qc.z,e2.z, qc.w*e2.w)));
            float d3 = fmaf(qd.x,e3.x, fmaf(qd.y,e3.y, fmaf(qd.z,e3.z, qd.w*e3.w)));
            qe_out[k] = (d0 + d1) + (d2 + d3);
        }
    }
}

// ---------------- attention: LDS-staged K/V tiles, KS=8 (2048 blocks, 4/CU) ----------
__global__ __launch_bounds__(256) void attn6_kernel(
    const float* __restrict__ Q, const float* __restrict__ K, const float* __restrict__ V,
    const float* __restrict__ QE, const float* __restrict__ coords,
    float* __restrict__ P)
{
    const int tid  = threadIdx.x;
    const int wave = tid >> 6;
    const int lane = tid & 63;
    const int bid  = blockIdx.x;
    const int ks    = bid & 7;
    const int chunk = (bid >> 3) & 7;
    const int h     = (bid >> 6) & (H_ - 1);
    const int b     = bid >> 9;
    const int row = b * N_ + chunk * 64 + lane;

    __shared__ float kl[64][16];
    __shared__ float vl[64][16];
    __shared__ float qel[64][NB + 1];
    __shared__ float ckrd[64][2];
    __shared__ float accl[4][64][17];

    const size_t hdbase = (size_t)b * N_ * D_ + h * DK;
    {
        int key = tid >> 2, part = tid & 3;
        size_t g = hdbase + (size_t)(ks * 64 + key) * D_ + part * 4;
        *(float4*)&kl[key][part * 4] = *(const float4*)&K[g];
        *(float4*)&vl[key][part * 4] = *(const float4*)&V[g];
    }
    {
        int r = tid >> 2, part = tid & 3;
        const float* src = QE + ((size_t)(b * N_ + chunk * 64 + r) * H_ + h) * NB + part * 8;
#pragma unroll
        for (int j = 0; j < 8; ++j) qel[r][part * 8 + j] = src[j];
    }
    if (tid < 128)
        ((float*)ckrd)[tid] = coords[(size_t)(b * N_ + ks * 64) * 2 + tid];

    const float4* qp = (const float4*)(Q + (size_t)row * D_ + h * DK);
    const float4 q0 = qp[0], q1 = qp[1], q2 = qp[2], q3 = qp[3];
    const float cx = coords[(size_t)row * 2 + 0];
    const float cy = coords[(size_t)row * 2 + 1];

    __syncthreads();

    float l = 0.f;
    float acc[16] = {};
    const int ml0 = wave * 16;
#pragma unroll 4
    for (int i = 0; i < 16; ++i) {
        const int ml = ml0 + i;
        float dx = cx - ckrd[ml][0], dy = cy - ckrd[ml][1];
        float dist = sqrtf(fmaf(dx, dx, dy * dy));
        int bucket = (int)(dist * 32.0f);
        bucket = bucket > (NB - 1) ? (NB - 1) : bucket;
        float qe = qel[lane][bucket];
        const float4* kp = (const float4*)&kl[ml][0];
        const float4 k0 = kp[0], k1 = kp[1], k2 = kp[2], k3 = kp[3];
        float d0 = fmaf(q0.x,k0.x, fmaf(q0.y,k0.y, fmaf(q0.z,k0.z, q0.w*k0.w)));
        float d1 = fmaf(q1.x,k1.x, fmaf(q1.y,k1.y, fmaf(q1.z,k1.z, q1.w*k1.w)));
        float d2 = fmaf(q2.x,k2.x, fmaf(q2.y,k2.y, fmaf(q2.z,k2.z, q2.w*k2.w)));
        float d3 = fmaf(q3.x,k3.x, fmaf(q3.y,k3.y, fmaf(q3.z,k3.z, q3.w*k3.w)));
        float p = __expf(fmaf((d0 + d1) + (d2 + d3), 0.25f, qe));
        l += p;
        const float4* vp = (const float4*)&vl[ml][0];
        const float4 v0 = vp[0], v1 = vp[1], v2 = vp[2], v3 = vp[3];
        acc[0]  += p * v0.x; acc[1]  += p * v0.y; acc[2]  += p * v0.z; acc[3]  += p * v0.w;
        acc[4]  += p * v1.x; acc[5]  += p * v1.y; acc[6]  += p * v1.z; acc[7]  += p * v1.w;
        acc[8]  += p * v2.x; acc[9]  += p * v2.y; acc[10] += p * v2.z; acc[11] += p * v2.w;
        acc[12] += p * v3.x; acc[13] += p * v3.y; acc[14] += p * v3.z; acc[15] += p * v3.w;
    }

    accl[wave][lane][16] = l;
#pragma unroll
    for (int j = 0; j < 16; ++j) accl[wave][lane][j] = acc[j];
    __syncthreads();

    float* pb = P + (size_t)bid * (64 * 17);
    for (int i = tid; i < 64 * 17; i += 256) {
        int r = i / 17, j = i - r * 17;
        pb[i] = accl[0][r][j] + accl[1][r][j] + accl[2][r][j] + accl[3][r][j];
    }
}

// ---------------- O-proj: combine + GEMV + residual (512 blocks, 4 rows, 2/CU) -------
__global__ __launch_bounds__(256) void oproj_kernel(
    const float* __restrict__ P, const float* __restrict__ WO,
    const float* __restrict__ hres, float* __restrict__ X1)
{
    const int tid = threadIdx.x;
    const int gr0 = blockIdx.x * 4;
    __shared__ float AOls[4][128];
    __shared__ float lsl[4][8];

    if (tid < 32) {
        int r = tid >> 3, hh = tid & 7;
        int gr = gr0 + r;
        int b = gr >> 9, n = gr & (N_ - 1);
        int chunk = n >> 6, rl = n & 63;
        size_t base = ((size_t)(((b * H_ + hh) * 8 + chunk) * KS)) * (64 * 17) + (size_t)rl * 17;
        float l = 0.f;
#pragma unroll
        for (int s = 0; s < KS; ++s) l += P[base + (size_t)s * (64 * 17) + 16];
        lsl[r][hh] = l;
    }
    float asum[2];
#pragma unroll
    for (int j = 0; j < 2; ++j) {
        int i = tid + j * 256;
        int r = i >> 7, d = i & 127;
        int gr = gr0 + r;
        int b = gr >> 9, n = gr & (N_ - 1);
        int chunk = n >> 6, rl = n & 63;
        int hh = d >> 4, dk = d & 15;
        size_t base = ((size_t)(((b * H_ + hh) * 8 + chunk) * KS)) * (64 * 17) + (size_t)rl * 17 + dk;
        float s = 0.f;
#pragma unroll
        for (int ss = 0; ss < KS; ++ss) s += P[base + (size_t)ss * (64 * 17)];
        asum[j] = s;
    }
    __syncthreads();
#pragma unroll
    for (int j = 0; j < 2; ++j) {
        int i = tid + j * 256;
        int r = i >> 7, d = i & 127;
        AOls[r][d] = asum[j] / lsl[r][d >> 4];
    }
    __syncthreads();

    const int wave = tid >> 6;
    const int lane = tid & 63;
    const int col = lane * 2;
    float acc0 = 0.f, acc1 = 0.f;
#pragma unroll 2
    for (int k0 = 0; k0 < D_; k0 += 4) {
        float4 av = *(const float4*)&AOls[wave][k0];
#pragma unroll
        for (int kk = 0; kk < 4; ++kk) {
            float2 bv = *(const float2*)&WO[(size_t)(k0 + kk) * D_ + col];
            float x = (&av.x)[kk];
            acc0 += x * bv.x; acc1 += x * bv.y;
        }
    }
    const int gr = gr0 + wave;
    float2 rv = *(const float2*)&hres[(size_t)gr * D_ + col];
    *(float2*)&X1[(size_t)gr * D_ + col] = make_float2(acc0 + rv.x, acc1 + rv.y);
}

// ---------------- instance-norm stats (128 blocks): T1 = r*g, T2 = be - m*r*g --------
__global__ __launch_bounds__(256) void stats_kernel(const float* __restrict__ X,
    const float* __restrict__ gamma, const float* __restrict__ beta,
    float* __restrict__ T1, float* __restrict__ T2)
{
    const int b  = blockIdx.x >> 5;
    const int dg = blockIdx.x & 31;
    const int dl = threadIdx.x & 3;
    const int nc = threadIdx.x >> 2;
    const float* xp = X + ((size_t)b * N_ + nc * 8) * D_ + dg * 4 + dl;
    float s = 0.f, q = 0.f;
#pragma unroll
    for (int i = 0; i < 8; ++i) { float x = xp[(size_t)i * D_]; s += x; q += x * x; }
    __shared__ float rs[64][4], rq[64][4];
    rs[nc][dl] = s; rq[nc][dl] = q;
    __syncthreads();
    for (int off = 32; off >= 1; off >>= 1) {
        if (nc < off) { rs[nc][dl] += rs[nc + off][dl]; rq[nc][dl] += rq[nc + off][dl]; }
        __syncthreads();
    }
    if (threadIdx.x < 4) {
        int d = dg * 4 + threadIdx.x;
        float mean = rs[0][threadIdx.x] * (1.0f / N_);
        float var  = rq[0][threadIdx.x] * (1.0f / N_) - mean * mean;
        float r = 1.0f / sqrtf(var + 1e-5f);
        float t1 = r * gamma[d];
        T1[b * D_ + d] = t1;
        T2[b * D_ + d] = beta[d] - mean * t1;
    }
}

// ---------------- FFN1: norm(X1) prologue; wave = 4 rows x 128-col slice (512 blk) ---
__global__ __launch_bounds__(256) void ffn1_kernel(
    const float* __restrict__ X1, const float* __restrict__ T1, const float* __restrict__ T2,
    const float* __restrict__ w1, const float* __restrict__ b1, float* __restrict__ F1)
{
    __shared__ float Als[16][128];
    const int gr0 = blockIdx.x * 16;
    const int b = gr0 >> 9;
#pragma unroll
    for (int i = threadIdx.x * 4; i < 16 * 128; i += 1024) {
        int r = i >> 7, c = i & 127;
        float4 x  = *(const float4*)&X1[(size_t)(gr0 + r) * D_ + c];
        float4 t1 = *(const float4*)&T1[b * D_ + c];
        float4 t2 = *(const float4*)&T2[b * D_ + c];
        float4 y;
        y.x = x.x * t1.x + t2.x; y.y = x.y * t1.y + t2.y;
        y.z = x.z * t1.z + t2.z; y.w = x.w * t1.w + t2.w;
        *(float4*)&Als[r][c] = y;
    }
    __syncthreads();

    const int wave = threadIdx.x >> 6;
    const int lane = threadIdx.x & 63;
    const int rl = wave * 4;
    const int col = blockIdx.y * 128 + lane * 2;

    float acc[4][2] = {};
#pragma unroll 2
    for (int k0 = 0; k0 < D_; k0 += 4) {
        float4 a4[4];
#pragma unroll
        for (int j = 0; j < 4; ++j) a4[j] = *(const float4*)&Als[rl + j][k0];
#pragma unroll
        for (int kk = 0; kk < 4; ++kk) {
            float2 bv = *(const float2*)&w1[(size_t)(k0 + kk) * DFF + col];
#pragma unroll
            for (int j = 0; j < 4; ++j) {
                float x = (&a4[j].x)[kk];
                acc[j][0] += x * bv.x; acc[j][1] += x * bv.y;
            }
        }
    }
    float2 bb = *(const float2*)&b1[col];
#pragma unroll
    for (int j = 0; j < 4; ++j) {
        float o0 = fmaxf(acc[j][0] + bb.x, 0.f);
        float o1 = fmaxf(acc[j][1] + bb.y, 0.f);
        *(float2*)&F1[(size_t)(gr0 + rl + j) * DFF + col] = make_float2(o0, o1);
    }
}

// ---------------- FFN2 fused: in-block split-K + combine + b2 + norm1 residual -------
__global__ __launch_bounds__(256) void ffn2f_kernel(
    const float* __restrict__ F1, const float* __restrict__ w2, const float* __restrict__ b2,
    const float* __restrict__ X1, const float* __restrict__ T1, const float* __restrict__ T2,
    float* __restrict__ X2)
{
    const int tid = threadIdx.x;
    const int wave = tid >> 6;
    const int lane = tid & 63;
    const int gr0 = __builtin_amdgcn_readfirstlane(blockIdx.x * 4);
    const int kbeg = __builtin_amdgcn_readfirstlane(wave * 128);
    const int col = lane * 2;

    __shared__ float part[4][4][128];          // [wave][row][col] = 8KB

    float acc[4][2] = {};
#pragma unroll 2
    for (int k0 = kbeg; k0 < kbeg + 128; k0 += 4) {
        float4 a4[4];
#pragma unroll
        for (int j = 0; j < 4; ++j)
            a4[j] = *(const float4*)&F1[(size_t)(gr0 + j) * DFF + k0];
#pragma unroll
        for (int kk = 0; kk < 4; ++kk) {
            float2 bv = *(const float2*)&w2[(size_t)(k0 + kk) * D_ + col];
#pragma unroll
            for (int j = 0; j < 4; ++j) {
                float x = (&a4[j].x)[kk];
                acc[j][0] += x * bv.x; acc[j][1] += x * bv.y;
            }
        }
    }
#pragma unroll
    for (int j = 0; j < 4; ++j)
        *(float2*)&part[wave][j][col] = make_float2(acc[j][0], acc[j][1]);
    __syncthreads();

#pragma unroll
    for (int e = 0; e < 2; ++e) {
        int i = tid + e * 256;
        int r = i >> 7, c = i & 127;
        int row = gr0 + r;
        int b = row >> 9;
        float s = part[0][r][c] + part[1][r][c] + part[2][r][c] + part[3][r][c];
        float x1 = X1[(size_t)row * D_ + c];
        float o = s + b2[c] + (x1 * T1[b * D_ + c] + T2[b * D_ + c]);
        X2[(size_t)row * D_ + c] = o;
    }
}

// ---------------- fused instance-norm-2 stats + apply -> out (128 blocks) ------------
__global__ __launch_bounds__(256) void stats_apply_kernel(const float* __restrict__ X,
    const float* __restrict__ gamma, const float* __restrict__ beta,
    float* __restrict__ Y)
{
    const int b  = blockIdx.x >> 5;
    const int dg = blockIdx.x & 31;
    const int dl = threadIdx.x & 3;
    const int nc = threadIdx.x >> 2;
    const float* xp = X + ((size_t)b * N_ + nc * 8) * D_ + dg * 4 + dl;
    float s = 0.f, q = 0.f;
#pragma unroll
    for (int i = 0; i < 8; ++i) { float x = xp[(size_t)i * D_]; s += x; q += x * x; }
    __shared__ float rs[64][4], rq[64][4];
    __shared__ float t1l[4], t2l[4];
    rs[nc][dl] = s; rq[nc][dl] = q;
    __syncthreads();
    for (int off = 32; off >= 1; off >>= 1) {
        if (nc < off) { rs[nc][dl] += rs[nc + off][dl]; rq[nc][dl] += rq[nc + off][dl]; }
        __syncthreads();
    }
    if (threadIdx.x < 4) {
        int d = dg * 4 + threadIdx.x;
        float mean = rs[0][threadIdx.x] * (1.0f / N_);
        float var  = rq[0][threadIdx.x] * (1.0f / N_) - mean * mean;
        float r = 1.0f / sqrtf(var + 1e-5f);
        float t1 = r * gamma[d];
        t1l[threadIdx.x] = t1;
        t2l[threadIdx.x] = beta[d] - mean * t1;
    }
    __syncthreads();
    const float t1 = t1l[dl], t2 = t2l[dl];
    float* yp = Y + ((size_t)b * N_ + nc * 8) * D_ + dg * 4 + dl;
#pragma unroll
    for (int i = 0; i < 8; ++i) yp[(size_t)i * D_] = xp[(size_t)i * D_] * t1 + t2;
}

extern "C" void kernel_launch(void* const* d_in, const int* in_sizes, int n_in,
                              void* d_out, int out_size, void* d_ws, size_t ws_size,
                              hipStream_t stream)
{
    const float* h      = (const float*)d_in[0];
    const float* coords = (const float*)d_in[1];
    const float* W_Q    = (const float*)d_in[2];
    const float* W_K    = (const float*)d_in[3];
    const float* W_V    = (const float*)d_in[4];
    const float* W_O    = (const float*)d_in[5];
    const float* emb    = (const float*)d_in[6];
    const float* w1     = (const float*)d_in[7];
    const float* b1     = (const float*)d_in[8];
    const float* w2     = (const float*)d_in[9];
    const float* b2     = (const float*)d_in[10];
    const float* g1     = (const float*)d_in[11];
    const float* be1    = (const float*)d_in[12];
    const float* g2     = (const float*)d_in[13];
    const float* be2    = (const float*)d_in[14];
    float* out = (float*)d_out;

    float* ws = (float*)d_ws;
    const size_t R = (size_t)B_ * N_;          // 2048 rows
    float* Qb  = ws;
    float* Kb  = Qb + R * D_;
    float* Vb  = Kb + R * D_;
    float* QEb = Vb + R * D_;                  // R*H*NB
    float* X1  = QEb + R * H_ * NB;
    float* F1  = X1 + R * D_;                  // R * DFF
    float* X2  = F1 + R * DFF;
    float* Pb  = X2 + R * D_;                  // 2048 * 64 * 17
    float* T1a = Pb + (size_t)2048 * 64 * 17;
    float* T2a = T1a + B_ * D_;

    // 1. Q,K,V projections + QE table (384 blocks)
    qkv_qe_kernel<<<dim3(128, 1, 3), 256, 0, stream>>>(
        h, W_Q, W_K, W_V, emb, Qb, Kb, Vb, QEb);
    // 2. attention (KS=8; 2048 blocks) -> partials
    attn6_kernel<<<dim3(2048), 256, 0, stream>>>(Qb, Kb, Vb, QEb, coords, Pb);
    // 3. O-projection (combine prologue + residual h; 512 blocks, 2/CU)
    oproj_kernel<<<dim3((int)R / 4), 256, 0, stream>>>(Pb, W_O, h, X1);
    // 4. instance-norm-1 stats (128 blocks)
    stats_kernel<<<dim3(B_ * 32), 256, 0, stream>>>(X1, g1, be1, T1a, T2a);
    // 5. FFN1 (norm prologue; relu; 512 blocks)
    ffn1_kernel<<<dim3(128, 4), 256, 0, stream>>>(X1, T1a, T2a, w1, b1, F1);
    // 6. FFN2 fused split-K + combine + b2 + norm1(X1) residual (512 blocks)
    ffn2f_kernel<<<dim3((int)R / 4), 256, 0, stream>>>(F1, w2, b2, X1, T1a, T2a, X2);
    // 7. instance-norm-2 stats + apply -> out (128 blocks)
    stats_apply_kernel<<<dim3(B_ * 32), 256, 0, stream>>>(X2, g2, be2, out);
}

// Round 17
// 78.046 us; speedup vs baseline: 1.0254x; 1.0254x over previous
//
#include <hip/hip_runtime.h>
#include <hip/hip_bf16.h>

#define B_  4
#define N_  512
#define D_  128
#define H_  8
#define DK  16
#define DFF 512
#define NB  32
#define KS  8            // attention key-split

// ---------------- QKV projections + fused QE table (384 blocks, ROWS=4) --------------
__global__ __launch_bounds__(256) void qkv_qe_kernel(
    const float* __restrict__ A,
    const float* __restrict__ WQ, const float* __restrict__ WK, const float* __restrict__ WV,
    const float* __restrict__ emb,
    float* __restrict__ Qo, float* __restrict__ Ko, float* __restrict__ Vo,
    float* __restrict__ QE)
{
    const float* Bw = blockIdx.z == 0 ? WQ : (blockIdx.z == 1 ? WK : WV);
    float*       C  = blockIdx.z == 0 ? Qo : (blockIdx.z == 1 ? Ko : Vo);
    const int wave = threadIdx.x >> 6;
    const int lane = threadIdx.x & 63;
    const int rbase = __builtin_amdgcn_readfirstlane((blockIdx.x * 4 + wave) * 4);
    const int col = lane * 2;

    float acc[4][2] = {};
#pragma unroll 2
    for (int k0 = 0; k0 < D_; k0 += 4) {
        float4 a4[4];
#pragma unroll
        for (int j = 0; j < 4; ++j)
            a4[j] = *(const float4*)&A[(size_t)(rbase + j) * D_ + k0];
#pragma unroll
        for (int kk = 0; kk < 4; ++kk) {
            float2 bv = *(const float2*)&Bw[(size_t)(k0 + kk) * D_ + col];
#pragma unroll
            for (int j = 0; j < 4; ++j) {
                float x = (&a4[j].x)[kk];
                acc[j][0] += x * bv.x; acc[j][1] += x * bv.y;
            }
        }
    }
#pragma unroll
    for (int j = 0; j < 4; ++j)
        *(float2*)&C[(size_t)(rbase + j) * D_ + col] = make_float2(acc[j][0], acc[j][1]);

    if (blockIdx.z == 0) {
        __shared__ float Qls[16][132];
#pragma unroll
        for (int j = 0; j < 4; ++j)
            *(float2*)&Qls[wave * 4 + j][col] = make_float2(acc[j][0], acc[j][1]);
        __syncthreads();
        const int r  = threadIdx.x >> 4;
        const int hh = (threadIdx.x & 15) >> 1;
        const int k0 = (threadIdx.x & 1) * 16;
        const int grow = blockIdx.x * 16 + r;
        const float4* qv = (const float4*)&Qls[r][hh * DK];
        const float4 qa = qv[0], qb = qv[1], qc = qv[2], qd = qv[3];
        float* qe_out = QE + ((size_t)grow * H_ + hh) * NB + k0;
#pragma unroll 4
        for (int k = 0; k < 16; ++k) {
            const float4* ep = (const float4*)(emb + (size_t)(k0 + k) * D_ + hh * DK);
            float4 e0 = ep[0], e1 = ep[1], e2 = ep[2], e3 = ep[3];
            float d0 = fmaf(qa.x,e0.x, fmaf(qa.y,e0.y, fmaf(qa.z,e0.z, qa.w*e0.w)));
            float d1 = fmaf(qb.x,e1.x, fmaf(qb.y,e1.y, fmaf(qb.z,e1.z, qb.w*e1.w)));
            float d2 = fmaf(qc.x,e2.x, fmaf(qc.y,e2.y, fmaf(qc.z,e2.z, qc.w*e2.w)));
            float d3 = fmaf(qd.x,e3.x, fmaf(qd.y,e3.y, fmaf(qd.z,e3.z, qd.w*e3.w)));
            qe_out[k] = (d0 + d1) + (d2 + d3);
        }
    }
}

// ---------------- attention: LDS-staged K/V tiles, KS=8 (2048 blocks, 4/CU) ----------
__global__ __launch_bounds__(256) void attn6_kernel(
    const float* __restrict__ Q, const float* __restrict__ K, const float* __restrict__ V,
    const float* __restrict__ QE, const float* __restrict__ coords,
    float* __restrict__ P)
{
    const int tid  = threadIdx.x;
    const int wave = tid >> 6;
    const int lane = tid & 63;
    const int bid  = blockIdx.x;
    const int ks    = bid & 7;
    const int chunk = (bid >> 3) & 7;
    const int h     = (bid >> 6) & (H_ - 1);
    const int b     = bid >> 9;
    const int row = b * N_ + chunk * 64 + lane;

    __shared__ float kl[64][16];
    __shared__ float vl[64][16];
    __shared__ float qel[64][NB + 1];
    __shared__ float ckrd[64][2];
    __shared__ float accl[4][64][17];

    const size_t hdbase = (size_t)b * N_ * D_ + h * DK;
    {
        int key = tid >> 2, part = tid & 3;
        size_t g = hdbase + (size_t)(ks * 64 + key) * D_ + part * 4;
        *(float4*)&kl[key][part * 4] = *(const float4*)&K[g];
        *(float4*)&vl[key][part * 4] = *(const float4*)&V[g];
    }
    {
        int r = tid >> 2, part = tid & 3;
        const float* src = QE + ((size_t)(b * N_ + chunk * 64 + r) * H_ + h) * NB + part * 8;
#pragma unroll
        for (int j = 0; j < 8; ++j) qel[r][part * 8 + j] = src[j];
    }
    if (tid < 128)
        ((float*)ckrd)[tid] = coords[(size_t)(b * N_ + ks * 64) * 2 + tid];

    const float4* qp = (const float4*)(Q + (size_t)row * D_ + h * DK);
    const float4 q0 = qp[0], q1 = qp[1], q2 = qp[2], q3 = qp[3];
    const float cx = coords[(size_t)row * 2 + 0];
    const float cy = coords[(size_t)row * 2 + 1];

    __syncthreads();

    float l = 0.f;
    float acc[16] = {};
    const int ml0 = wave * 16;
#pragma unroll 4
    for (int i = 0; i < 16; ++i) {
        const int ml = ml0 + i;
        float dx = cx - ckrd[ml][0], dy = cy - ckrd[ml][1];
        float dist = sqrtf(fmaf(dx, dx, dy * dy));
        int bucket = (int)(dist * 32.0f);
        bucket = bucket > (NB - 1) ? (NB - 1) : bucket;
        float qe = qel[lane][bucket];
        const float4* kp = (const float4*)&kl[ml][0];
        const float4 k0 = kp[0], k1 = kp[1], k2 = kp[2], k3 = kp[3];
        float d0 = fmaf(q0.x,k0.x, fmaf(q0.y,k0.y, fmaf(q0.z,k0.z, q0.w*k0.w)));
        float d1 = fmaf(q1.x,k1.x, fmaf(q1.y,k1.y, fmaf(q1.z,k1.z, q1.w*k1.w)));
        float d2 = fmaf(q2.x,k2.x, fmaf(q2.y,k2.y, fmaf(q2.z,k2.z, q2.w*k2.w)));
        float d3 = fmaf(q3.x,k3.x, fmaf(q3.y,k3.y, fmaf(q3.z,k3.z, q3.w*k3.w)));
        float p = __expf(fmaf((d0 + d1) + (d2 + d3), 0.25f, qe));
        l += p;
        const float4* vp = (const float4*)&vl[ml][0];
        const float4 v0 = vp[0], v1 = vp[1], v2 = vp[2], v3 = vp[3];
        acc[0]  += p * v0.x; acc[1]  += p * v0.y; acc[2]  += p * v0.z; acc[3]  += p * v0.w;
        acc[4]  += p * v1.x; acc[5]  += p * v1.y; acc[6]  += p * v1.z; acc[7]  += p * v1.w;
        acc[8]  += p * v2.x; acc[9]  += p * v2.y; acc[10] += p * v2.z; acc[11] += p * v2.w;
        acc[12] += p * v3.x; acc[13] += p * v3.y; acc[14] += p * v3.z; acc[15] += p * v3.w;
    }

    accl[wave][lane][16] = l;
#pragma unroll
    for (int j = 0; j < 16; ++j) accl[wave][lane][j] = acc[j];
    __syncthreads();

    float* pb = P + (size_t)bid * (64 * 17);
    for (int i = tid; i < 64 * 17; i += 256) {
        int r = i / 17, j = i - r * 17;
        pb[i] = accl[0][r][j] + accl[1][r][j] + accl[2][r][j] + accl[3][r][j];
    }
}

// ---------------- O-proj: combine KS partials + ROWS=2 GEMV + h residual (256 blk) ---
__global__ __launch_bounds__(256) void oproj_kernel(
    const float* __restrict__ P, const float* __restrict__ WO,
    const float* __restrict__ hres, float* __restrict__ X1)
{
    const int tid = threadIdx.x;
    const int gr0 = blockIdx.x * 8;
    __shared__ float AOls[8][128];
    __shared__ float lsl[8][8];

    if (tid < 64) {
        int r = tid >> 3, hh = tid & 7;
        int gr = gr0 + r;
        int b = gr >> 9, n = gr & (N_ - 1);
        int chunk = n >> 6, rl = n & 63;
        size_t base = ((size_t)(((b * H_ + hh) * 8 + chunk) * KS)) * (64 * 17) + (size_t)rl * 17;
        float l = 0.f;
#pragma unroll
        for (int s = 0; s < KS; ++s) l += P[base + (size_t)s * (64 * 17) + 16];
        lsl[r][hh] = l;
    }
    float asum[4];
#pragma unroll
    for (int j = 0; j < 4; ++j) {
        int i = tid + j * 256;
        int r = i >> 7, d = i & 127;
        int gr = gr0 + r;
        int b = gr >> 9, n = gr & (N_ - 1);
        int chunk = n >> 6, rl = n & 63;
        int hh = d >> 4, dk = d & 15;
        size_t base = ((size_t)(((b * H_ + hh) * 8 + chunk) * KS)) * (64 * 17) + (size_t)rl * 17 + dk;
        float s = 0.f;
#pragma unroll
        for (int ss = 0; ss < KS; ++ss) s += P[base + (size_t)ss * (64 * 17)];
        asum[j] = s;
    }
    __syncthreads();
#pragma unroll
    for (int j = 0; j < 4; ++j) {
        int i = tid + j * 256;
        int r = i >> 7, d = i & 127;
        AOls[r][d] = asum[j] / lsl[r][d >> 4];
    }
    __syncthreads();

    const int wave = tid >> 6;
    const int lane = tid & 63;
    const int rl = wave * 2;
    const int grb = __builtin_amdgcn_readfirstlane(gr0 + rl);
    const int col = lane * 2;

    float acc[2][2] = {};
#pragma unroll 2
    for (int k0 = 0; k0 < D_; k0 += 4) {
        float4 a0 = *(const float4*)&AOls[rl + 0][k0];
        float4 a1 = *(const float4*)&AOls[rl + 1][k0];
#pragma unroll
        for (int kk = 0; kk < 4; ++kk) {
            float2 bv = *(const float2*)&WO[(size_t)(k0 + kk) * D_ + col];
            float x0 = (&a0.x)[kk], x1 = (&a1.x)[kk];
            acc[0][0] += x0 * bv.x; acc[0][1] += x0 * bv.y;
            acc[1][0] += x1 * bv.x; acc[1][1] += x1 * bv.y;
        }
    }
#pragma unroll
    for (int j = 0; j < 2; ++j) {
        float2 rv = *(const float2*)&hres[(size_t)(grb + j) * D_ + col];
        *(float2*)&X1[(size_t)(grb + j) * D_ + col] =
            make_float2(acc[j][0] + rv.x, acc[j][1] + rv.y);
    }
}

// ---------------- instance-norm stats (128 blocks): T1 = r*g, T2 = be - m*r*g --------
__global__ __launch_bounds__(256) void stats_kernel(const float* __restrict__ X,
    const float* __restrict__ gamma, const float* __restrict__ beta,
    float* __restrict__ T1, float* __restrict__ T2)
{
    const int b  = blockIdx.x >> 5;
    const int dg = blockIdx.x & 31;
    const int dl = threadIdx.x & 3;
    const int nc = threadIdx.x >> 2;
    const float* xp = X + ((size_t)b * N_ + nc * 8) * D_ + dg * 4 + dl;
    float s = 0.f, q = 0.f;
#pragma unroll
    for (int i = 0; i < 8; ++i) { float x = xp[(size_t)i * D_]; s += x; q += x * x; }
    __shared__ float rs[64][4], rq[64][4];
    rs[nc][dl] = s; rq[nc][dl] = q;
    __syncthreads();
    for (int off = 32; off >= 1; off >>= 1) {
        if (nc < off) { rs[nc][dl] += rs[nc + off][dl]; rq[nc][dl] += rq[nc + off][dl]; }
        __syncthreads();
    }
    if (threadIdx.x < 4) {
        int d = dg * 4 + threadIdx.x;
        float mean = rs[0][threadIdx.x] * (1.0f / N_);
        float var  = rq[0][threadIdx.x] * (1.0f / N_) - mean * mean;
        float r = 1.0f / sqrtf(var + 1e-5f);
        float t1 = r * gamma[d];
        T1[b * D_ + d] = t1;
        T2[b * D_ + d] = beta[d] - mean * t1;
    }
}

// ---------------- FFN1: norm(X1) prologue; wave = 4 rows x 128-col slice (512 blk) ---
__global__ __launch_bounds__(256) void ffn1_kernel(
    const float* __restrict__ X1, const float* __restrict__ T1, const float* __restrict__ T2,
    const float* __restrict__ w1, const float* __restrict__ b1, float* __restrict__ F1)
{
    __shared__ float Als[16][128];
    const int gr0 = blockIdx.x * 16;
    const int b = gr0 >> 9;
#pragma unroll
    for (int i = threadIdx.x * 4; i < 16 * 128; i += 1024) {
        int r = i >> 7, c = i & 127;
        float4 x  = *(const float4*)&X1[(size_t)(gr0 + r) * D_ + c];
        float4 t1 = *(const float4*)&T1[b * D_ + c];
        float4 t2 = *(const float4*)&T2[b * D_ + c];
        float4 y;
        y.x = x.x * t1.x + t2.x; y.y = x.y * t1.y + t2.y;
        y.z = x.z * t1.z + t2.z; y.w = x.w * t1.w + t2.w;
        *(float4*)&Als[r][c] = y;
    }
    __syncthreads();

    const int wave = threadIdx.x >> 6;
    const int lane = threadIdx.x & 63;
    const int rl = wave * 4;
    const int col = blockIdx.y * 128 + lane * 2;

    float acc[4][2] = {};
#pragma unroll 2
    for (int k0 = 0; k0 < D_; k0 += 4) {
        float4 a4[4];
#pragma unroll
        for (int j = 0; j < 4; ++j) a4[j] = *(const float4*)&Als[rl + j][k0];
#pragma unroll
        for (int kk = 0; kk < 4; ++kk) {
            float2 bv = *(const float2*)&w1[(size_t)(k0 + kk) * DFF + col];
#pragma unroll
            for (int j = 0; j < 4; ++j) {
                float x = (&a4[j].x)[kk];
                acc[j][0] += x * bv.x; acc[j][1] += x * bv.y;
            }
        }
    }
    float2 bb = *(const float2*)&b1[col];
#pragma unroll
    for (int j = 0; j < 4; ++j) {
        float o0 = fmaxf(acc[j][0] + bb.x, 0.f);
        float o1 = fmaxf(acc[j][1] + bb.y, 0.f);
        *(float2*)&F1[(size_t)(gr0 + rl + j) * DFF + col] = make_float2(o0, o1);
    }
}

// ---------------- FFN2 fused: in-block split-K + combine + b2 + norm1 residual -------
__global__ __launch_bounds__(256) void ffn2f_kernel(
    const float* __restrict__ F1, const float* __restrict__ w2, const float* __restrict__ b2,
    const float* __restrict__ X1, const float* __restrict__ T1, const float* __restrict__ T2,
    float* __restrict__ X2)
{
    const int tid = threadIdx.x;
    const int wave = tid >> 6;
    const int lane = tid & 63;
    const int gr0 = __builtin_amdgcn_readfirstlane(blockIdx.x * 4);
    const int kbeg = __builtin_amdgcn_readfirstlane(wave * 128);
    const int col = lane * 2;

    __shared__ float part[4][4][128];          // [wave][row][col] = 8KB

    float acc[4][2] = {};
#pragma unroll 2
    for (int k0 = kbeg; k0 < kbeg + 128; k0 += 4) {
        float4 a4[4];
#pragma unroll
        for (int j = 0; j < 4; ++j)
            a4[j] = *(const float4*)&F1[(size_t)(gr0 + j) * DFF + k0];
#pragma unroll
        for (int kk = 0; kk < 4; ++kk) {
            float2 bv = *(const float2*)&w2[(size_t)(k0 + kk) * D_ + col];
#pragma unroll
            for (int j = 0; j < 4; ++j) {
                float x = (&a4[j].x)[kk];
                acc[j][0] += x * bv.x; acc[j][1] += x * bv.y;
            }
        }
    }
#pragma unroll
    for (int j = 0; j < 4; ++j)
        *(float2*)&part[wave][j][col] = make_float2(acc[j][0], acc[j][1]);
    __syncthreads();

#pragma unroll
    for (int e = 0; e < 2; ++e) {
        int i = tid + e * 256;
        int r = i >> 7, c = i & 127;
        int row = gr0 + r;
        int b = row >> 9;
        float s = part[0][r][c] + part[1][r][c] + part[2][r][c] + part[3][r][c];
        float x1 = X1[(size_t)row * D_ + c];
        float o = s + b2[c] + (x1 * T1[b * D_ + c] + T2[b * D_ + c]);
        X2[(size_t)row * D_ + c] = o;
    }
}

// ---------------- fused instance-norm-2 stats + apply -> out (128 blocks) ------------
__global__ __launch_bounds__(256) void stats_apply_kernel(const float* __restrict__ X,
    const float* __restrict__ gamma, const float* __restrict__ beta,
    float* __restrict__ Y)
{
    const int b  = blockIdx.x >> 5;
    const int dg = blockIdx.x & 31;
    const int dl = threadIdx.x & 3;
    const int nc = threadIdx.x >> 2;
    const float* xp = X + ((size_t)b * N_ + nc * 8) * D_ + dg * 4 + dl;
    float s = 0.f, q = 0.f;
#pragma unroll
    for (int i = 0; i < 8; ++i) { float x = xp[(size_t)i * D_]; s += x; q += x * x; }
    __shared__ float rs[64][4], rq[64][4];
    __shared__ float t1l[4], t2l[4];
    rs[nc][dl] = s; rq[nc][dl] = q;
    __syncthreads();
    for (int off = 32; off >= 1; off >>= 1) {
        if (nc < off) { rs[nc][dl] += rs[nc + off][dl]; rq[nc][dl] += rq[nc + off][dl]; }
        __syncthreads();
    }
    if (threadIdx.x < 4) {
        int d = dg * 4 + threadIdx.x;
        float mean = rs[0][threadIdx.x] * (1.0f / N_);
        float var  = rq[0][threadIdx.x] * (1.0f / N_) - mean * mean;
        float r = 1.0f / sqrtf(var + 1e-5f);
        float t1 = r * gamma[d];
        t1l[threadIdx.x] = t1;
        t2l[threadIdx.x] = beta[d] - mean * t1;
    }
    __syncthreads();
    const float t1 = t1l[dl], t2 = t2l[dl];
    float* yp = Y + ((size_t)b * N_ + nc * 8) * D_ + dg * 4 + dl;
#pragma unroll
    for (int i = 0; i < 8; ++i) yp[(size_t)i * D_] = xp[(size_t)i * D_] * t1 + t2;
}

extern "C" void kernel_launch(void* const* d_in, const int* in_sizes, int n_in,
                              void* d_out, int out_size, void* d_ws, size_t ws_size,
                              hipStream_t stream)
{
    const float* h      = (const float*)d_in[0];
    const float* coords = (const float*)d_in[1];
    const float* W_Q    = (const float*)d_in[2];
    const float* W_K    = (const float*)d_in[3];
    const float* W_V    = (const float*)d_in[4];
    const float* W_O    = (const float*)d_in[5];
    const float* emb    = (const float*)d_in[6];
    const float* w1     = (const float*)d_in[7];
    const float* b1     = (const float*)d_in[8];
    const float* w2     = (const float*)d_in[9];
    const float* b2     = (const float*)d_in[10];
    const float* g1     = (const float*)d_in[11];
    const float* be1    = (const float*)d_in[12];
    const float* g2     = (const float*)d_in[13];
    const float* be2    = (const float*)d_in[14];
    float* out = (float*)d_out;

    float* ws = (float*)d_ws;
    const size_t R = (size_t)B_ * N_;          // 2048 rows
    float* Qb  = ws;
    float* Kb  = Qb + R * D_;
    float* Vb  = Kb + R * D_;
    float* QEb = Vb + R * D_;                  // R*H*NB
    float* X1  = QEb + R * H_ * NB;
    float* F1  = X1 + R * D_;                  // R * DFF
    float* X2  = F1 + R * DFF;
    float* Pb  = X2 + R * D_;                  // 2048 * 64 * 17
    float* T1a = Pb + (size_t)2048 * 64 * 17;
    float* T2a = T1a + B_ * D_;

    // 1. Q,K,V projections + QE table (384 blocks)
    qkv_qe_kernel<<<dim3(128, 1, 3), 256, 0, stream>>>(
        h, W_Q, W_K, W_V, emb, Qb, Kb, Vb, QEb);
    // 2. attention (KS=8; 2048 blocks) -> partials
    attn6_kernel<<<dim3(2048), 256, 0, stream>>>(Qb, Kb, Vb, QEb, coords, Pb);
    // 3. O-projection (combine prologue + residual h; 256 blocks)
    oproj_kernel<<<dim3((int)R / 8), 256, 0, stream>>>(Pb, W_O, h, X1);
    // 4. instance-norm-1 stats (128 blocks)
    stats_kernel<<<dim3(B_ * 32), 256, 0, stream>>>(X1, g1, be1, T1a, T2a);
    // 5. FFN1 (norm prologue; relu; 512 blocks)
    ffn1_kernel<<<dim3(128, 4), 256, 0, stream>>>(X1, T1a, T2a, w1, b1, F1);
    // 6. FFN2 fused split-K + combine + b2 + norm1(X1) residual (512 blocks)
    ffn2f_kernel<<<dim3((int)R / 4), 256, 0, stream>>>(F1, w2, b2, X1, T1a, T2a, X2);
    // 7. instance-norm-2 stats + apply -> out (128 blocks)
    stats_apply_kernel<<<dim3(B_ * 32), 256, 0, stream>>>(X2, g2, be2, out);
}